// Round 2
// baseline (967.478 us; speedup 1.0000x reference)
//
#include <hip/hip_runtime.h>
#include <hip/hip_bf16.h>

// GlobalLocalAttention on MI355X — compact-workspace revision (237 MB).
// Regions: A=[0,64MiB) x_t -> dwt ; B=[64,160MiB) qkv_half -> outsum(bf16) ;
//          C=[160,224MiB) local(bf16) -> dw_nchw(bf16) ; W=weights (~1.7MB).
// d_out doubles as the f32 attention-output scratch (final GEMM rewrites it).
// qkv+attn split into channel halves: windows i1<16 read only NCHW planes
// c<384 of qkv (flat-view scramble is contiguous), i1>=16 read c>=384.

typedef __bf16 bf16x8 __attribute__((ext_vector_type(8)));
typedef float  f32x4  __attribute__((ext_vector_type(4)));
typedef unsigned short u16;

#define HWPIX 65536
#define NPIX  131072

__device__ __forceinline__ u16 f2bf(float f) {
    union { float f; unsigned u; } v; v.f = f;
    return (u16)((v.u + 0x7fffu + ((v.u >> 16) & 1u)) >> 16);
}
__device__ __forceinline__ float bf2f(u16 h) {
    union { unsigned u; float f; } v; v.u = ((unsigned)h) << 16;
    return v.f;
}

#define GLDS16(gp, lp) __builtin_amdgcn_global_load_lds( \
    (__attribute__((address_space(1))) void*)(gp), \
    (__attribute__((address_space(3))) void*)(lp), 16, 0, 0)

// ---------------------------------------------------------------------------
__global__ void prep_weights(const float* __restrict__ w_qkv,
                             const float* __restrict__ w_l1,
                             const float* __restrict__ bn1g, const float* __restrict__ bn1b,
                             const float* __restrict__ w_l2,
                             const float* __restrict__ bn2g, const float* __restrict__ bn2b,
                             const float* __restrict__ w_pw,
                             const float* __restrict__ bn3g, const float* __restrict__ bn3b,
                             u16* __restrict__ wl, u16* __restrict__ wq, u16* __restrict__ wpw,
                             float* __restrict__ bias_l, float* __restrict__ bias_pw,
                             u16* __restrict__ zeros)
{
    const int tid = threadIdx.x;
    if (blockIdx.x >= 256) {
        int row = blockIdx.x - 256;              // 0..767
        wq[row * 256 + tid] = f2bf(w_qkv[row * 256 + tid]);
        return;
    }
    const int oc = blockIdx.x, ic = tid;
    const float rs = rsqrtf(1.f + 1e-5f);
    const float s1 = bn1g[oc] * rs;
    const float s2 = bn2g[oc] * rs;
    const float w2v = w_l2[oc * 256 + ic] * s2;
    #pragma unroll
    for (int tap = 0; tap < 9; ++tap) {
        float v = s1 * w_l1[(oc * 256 + ic) * 9 + tap];
        if (tap == 4) v += w2v;
        wl[oc * 2304 + tap * 256 + ic] = f2bf(v);
    }
    const float s3 = bn3g[ic] * rs;
    const float wp = w_pw[oc * 256 + ic];
    wpw[oc * 256 + ic] = f2bf(wp * s3);

    __shared__ float red[256];
    red[ic] = wp * bn3b[ic];
    __syncthreads();
    for (int s = 128; s > 0; s >>= 1) {
        if (ic < s) red[ic] += red[ic + s];
        __syncthreads();
    }
    if (ic == 0) {
        bias_pw[oc] = red[0];
        bias_l[oc]  = bn1b[oc] + bn2b[oc];
    }
    if (blockIdx.x == 0) zeros[tid] = 0;
}

// ---------------------------------------------------------------------------
template <typename TIN>
__device__ __forceinline__ float ldval(const TIN* p);
template <> __device__ __forceinline__ float ldval<float>(const float* p) { return *p; }
template <> __device__ __forceinline__ float ldval<u16>(const u16* p)     { return bf2f(*p); }

template <typename TIN>
__global__ __launch_bounds__(256)
void to_chlast(const TIN* __restrict__ in, u16* __restrict__ out)
{
    __shared__ float L[32][65];
    const int tid = threadIdx.x;
    const int p0 = blockIdx.x * 64;
    const int b = p0 >> 16, pin = p0 & 65535;
    const TIN* src = in + (size_t)b * 256 * HWPIX + pin;
    for (int cb = 0; cb < 256; cb += 32) {
        #pragma unroll
        for (int e = 0; e < 8; ++e) {
            int idx = e * 256 + tid;
            int row = idx >> 6, px = idx & 63;
            L[row][px] = ldval(src + (size_t)(cb + row) * HWPIX + px);
        }
        __syncthreads();
        const int px = tid >> 2, cq = tid & 3;
        u16 t[8];
        #pragma unroll
        for (int e = 0; e < 8; ++e) t[e] = f2bf(L[cq * 8 + e][px]);
        uint4 v;
        v.x = (unsigned)t[0] | ((unsigned)t[1] << 16);
        v.y = (unsigned)t[2] | ((unsigned)t[3] << 16);
        v.z = (unsigned)t[4] | ((unsigned)t[5] << 16);
        v.w = (unsigned)t[6] | ((unsigned)t[7] << 16);
        *(uint4*)(out + (size_t)(p0 + px) * 256 + cb + cq * 8) = v;
        __syncthreads();
    }
}

// ---------------------------------------------------------------------------
// Implicit-GEMM conv (1x1 or 3x3): 128px x 128oc tile, BK=32, GLDS(16B),
// mfma_f32_16x16x32_bf16. Output plane index = bb*out_c + (oc - oc_off).
template <int NTAPS, bool OUT_BF16, bool HAS_BIAS>
__global__ __launch_bounds__(256)
void gemm_conv(const u16* __restrict__ X,
               const u16* __restrict__ Wm,
               const float* __restrict__ bias,
               void* __restrict__ outv,
               const u16* __restrict__ zeros,
               int oc_off, int out_c)
{
    constexpr int K = NTAPS * 256;
    __shared__ __align__(16) u16 Wt[128 * 32];
    __shared__ __align__(16) u16 Xt[128 * 32];

    const int tid   = threadIdx.x;
    const int wv    = tid >> 6;
    const int lane  = tid & 63;
    const int pbase = blockIdx.x * 128;
    const int obase = blockIdx.y * 128 + oc_off;
    const int srow  = wv * 16 + (lane >> 2);
    const int sslot = lane & 3;
    const int wr = wv >> 1, wc = wv & 1;

    f32x4 acc[4][4];
    #pragma unroll
    for (int o = 0; o < 4; ++o)
        #pragma unroll
        for (int p = 0; p < 4; ++p)
            acc[o][p] = (f32x4){0.f, 0.f, 0.f, 0.f};

    for (int tap = 0; tap < NTAPS; ++tap) {
        const u16* xsrc[2];
        const u16* wsrc[2];
        #pragma unroll
        for (int i = 0; i < 2; ++i) {
            const int row = i * 64 + srow;
            const int p = pbase + row;
            const u16* sp;
            if (NTAPS == 9) {
                const int dy = tap / 3 - 1, dx = tap % 3 - 1;
                const int h = (p >> 8) & 255, w = p & 255;
                const int hh = h + dy, ww = w + dx;
                if ((unsigned)hh < 256u && (unsigned)ww < 256u)
                    sp = X + (size_t)(p + dy * 256 + dx) * 256 + sslot * 8;
                else
                    sp = zeros + sslot * 8;
            } else {
                sp = X + (size_t)p * 256 + sslot * 8;
            }
            xsrc[i] = sp;
            wsrc[i] = Wm + (size_t)(obase + row) * K + tap * 256 + sslot * 8;
        }

        for (int kc = 0; kc < 256; kc += 32) {
            GLDS16(wsrc[0] + kc, &Wt[(wv * 16) * 32]);
            GLDS16(wsrc[1] + kc, &Wt[(64 + wv * 16) * 32]);
            GLDS16(xsrc[0] + kc, &Xt[(wv * 16) * 32]);
            GLDS16(xsrc[1] + kc, &Xt[(64 + wv * 16) * 32]);
            __syncthreads();

            bf16x8 afr[4], bfr[4];
            #pragma unroll
            for (int o = 0; o < 4; ++o)
                afr[o] = *(const bf16x8*)&Wt[(wr * 64 + o * 16 + (lane & 15)) * 32 + (lane >> 4) * 8];
            #pragma unroll
            for (int p = 0; p < 4; ++p)
                bfr[p] = *(const bf16x8*)&Xt[(wc * 64 + p * 16 + (lane & 15)) * 32 + (lane >> 4) * 8];
            #pragma unroll
            for (int o = 0; o < 4; ++o)
                #pragma unroll
                for (int p = 0; p < 4; ++p)
                    acc[o][p] = __builtin_amdgcn_mfma_f32_16x16x32_bf16(afr[o], bfr[p], acc[o][p], 0, 0, 0);
            __syncthreads();
        }
    }

    const int r0 = (lane >> 4) * 4;
    const int cl = lane & 15;
    #pragma unroll
    for (int o = 0; o < 4; ++o) {
        const int oc = obase + wr * 64 + o * 16 + r0;
        #pragma unroll
        for (int p = 0; p < 4; ++p) {
            const int px = pbase + wc * 64 + p * 16 + cl;
            const int bb = px >> 16, pin = px & 65535;
            const size_t base = ((size_t)bb * out_c + (oc - oc_off)) * HWPIX + pin;
            #pragma unroll
            for (int r = 0; r < 4; ++r) {
                float v = acc[o][p][r];
                if (HAS_BIAS) v += bias[oc + r];
                if (OUT_BF16) ((u16*)outv)[base + (size_t)r * HWPIX] = f2bf(v);
                else          ((float*)outv)[base + (size_t)r * HWPIX] = v;
            }
        }
    }
}

// ---------------------------------------------------------------------------
__device__ __forceinline__ void unp8(uint4 u, float* f) {
    f[0] = bf2f((u16)(u.x & 0xffff)); f[1] = bf2f((u16)(u.x >> 16));
    f[2] = bf2f((u16)(u.y & 0xffff)); f[3] = bf2f((u16)(u.y >> 16));
    f[4] = bf2f((u16)(u.z & 0xffff)); f[5] = bf2f((u16)(u.z >> 16));
    f[6] = bf2f((u16)(u.w & 0xffff)); f[7] = bf2f((u16)(u.w >> 16));
}

// One wave per (window, head); lane = query token. qkvh = half-buffer
// [2][384][65536] bf16 (NCHW planes c' = c - 384*half). i1 = i1l + i1_off.
__global__ __launch_bounds__(64)
void attn_win(const u16* __restrict__ qkvh,
              const float* __restrict__ rpb,
              float* __restrict__ outb, int i1_off)
{
    __shared__ float kls[64][16];
    __shared__ float vls[64][16];
    const int bid = blockIdx.x;               // 16384 blocks
    const int head = bid & 15;
    const int m = bid >> 4;                   // 0..1023
    const int b = m >> 9, i1l = (m >> 5) & 15, i3 = m & 31;
    const int t = threadIdx.x;
    const int i2 = t >> 3, i4 = t & 7;
    const size_t toff = (size_t)b * 25165824 + (size_t)i1l * 1572864 +
                        (size_t)i2 * 196608 + (size_t)i3 * 6144 + (size_t)i4 * 768 +
                        (size_t)head * 16;
    const uint4* qp = (const uint4*)(qkvh + toff);
    const uint4 q0 = qp[0],  q1 = qp[1];
    const uint4 k0 = qp[32], k1 = qp[33];
    const uint4 v0 = qp[64], v1 = qp[65];
    float qf[16], tmp[16];
    unp8(q0, qf); unp8(q1, qf + 8);
    unp8(k0, tmp); unp8(k1, tmp + 8);
    #pragma unroll
    for (int d = 0; d < 16; ++d) kls[t][d] = tmp[d];
    unp8(v0, tmp); unp8(v1, tmp + 8);
    #pragma unroll
    for (int d = 0; d < 16; ++d) vls[t][d] = tmp[d];
    __syncthreads();

    const int qi = t >> 3, qj = t & 7;
    float s[64];
    float mx = -1e30f;
    #pragma unroll
    for (int kt = 0; kt < 64; ++kt) {
        const float4 a  = *(const float4*)&kls[kt][0];
        const float4 b4 = *(const float4*)&kls[kt][4];
        const float4 c4 = *(const float4*)&kls[kt][8];
        const float4 d4 = *(const float4*)&kls[kt][12];
        float dot = qf[0]*a.x  + qf[1]*a.y  + qf[2]*a.z  + qf[3]*a.w
                  + qf[4]*b4.x + qf[5]*b4.y + qf[6]*b4.z + qf[7]*b4.w
                  + qf[8]*c4.x + qf[9]*c4.y + qf[10]*c4.z + qf[11]*c4.w
                  + qf[12]*d4.x+ qf[13]*d4.y+ qf[14]*d4.z+ qf[15]*d4.w;
        const int ki = kt >> 3, kj = kt & 7;
        const float val = dot * 0.25f + rpb[((qi - ki + 7) * 15 + (qj - kj + 7)) * 16 + head];
        s[kt] = val;
        mx = fmaxf(mx, val);
    }
    float l = 0.f;
    #pragma unroll
    for (int kt = 0; kt < 64; ++kt) { float e = __expf(s[kt] - mx); s[kt] = e; l += e; }
    const float inv = 1.f / l;
    float o[16];
    #pragma unroll
    for (int d = 0; d < 16; ++d) o[d] = 0.f;
    #pragma unroll
    for (int kt = 0; kt < 64; ++kt) {
        const float w = s[kt];
        const float4 a  = *(const float4*)&vls[kt][0];
        const float4 b4 = *(const float4*)&vls[kt][4];
        const float4 c4 = *(const float4*)&vls[kt][8];
        const float4 d4 = *(const float4*)&vls[kt][12];
        o[0] += w*a.x;  o[1] += w*a.y;  o[2]  += w*a.z;  o[3]  += w*a.w;
        o[4] += w*b4.x; o[5] += w*b4.y; o[6]  += w*b4.z; o[7]  += w*b4.w;
        o[8] += w*c4.x; o[9] += w*c4.y; o[10] += w*c4.z; o[11] += w*c4.w;
        o[12]+= w*d4.x; o[13]+= w*d4.y; o[14] += w*d4.z; o[15] += w*d4.w;
    }
    const int n = b * 1024 + (i1l + i1_off) * 32 + i3;   // global window id
    float* op = outb + ((size_t)(n * 16 + head) << 10) + t * 16;
    #pragma unroll
    for (int d = 0; d < 16; ++d) op[d] = o[d] * inv;
}

// ---------------------------------------------------------------------------
__device__ __forceinline__ bool extidx(int g, int& e) {
    e = (g == 256) ? 254 : g;
    return (unsigned)e < 256u;
}

// ax + ay + local -> outsum (bf16). attn input is f32 (= d_out scratch).
__global__ __launch_bounds__(256)
void pool_add(const float* __restrict__ attn, const u16* __restrict__ local,
              u16* __restrict__ outsum)
{
    __shared__ float S[39][40];
    const int bid = blockIdx.x;
    const int plane = bid >> 6;
    const int tile = bid & 63;
    const int th = (tile >> 3) * 32, tw = (tile & 7) * 32;
    const float* A = attn + (size_t)plane * HWPIX;
    const int tid = threadIdx.x;
    #pragma unroll
    for (int e = 0; e < 6; ++e) {
        const int idx = e * 256 + tid;
        if (idx < 39 * 39) {
            const int i = idx / 39, j = idx % 39;
            int eh, ew;
            const bool vh = extidx(th + i - 3, eh);
            const bool vw = extidx(tw + j - 3, ew);
            S[i][j] = (vh && vw) ? A[eh * 256 + ew] : 0.f;
        }
    }
    __syncthreads();
    const int ox = tid & 31, oy4 = (tid >> 5) * 4;
    const u16* L = local + (size_t)plane * HWPIX;
    u16* O = outsum + (size_t)plane * HWPIX;
    #pragma unroll
    for (int q = 0; q < 4; ++q) {
        const int oy = oy4 + q;
        float ax = 0.f, ay = 0.f;
        #pragma unroll
        for (int j = 0; j < 8; ++j) { ax += S[oy + j][ox + 3]; ay += S[oy + 3][ox + j]; }
        const int gh = th + oy, gw = tw + ox;
        O[gh * 256 + gw] = f2bf(0.125f * (ax + ay) + bf2f(L[gh * 256 + gw]));
    }
}

// reflect(0,1) + zero-pad(3) + depthwise 8x8; bf16 in/out
__global__ __launch_bounds__(256)
void dwconv(const u16* __restrict__ outsum, const float* __restrict__ wdw,
            u16* __restrict__ dwo)
{
    __shared__ float S[39][40];
    __shared__ float wk[64];
    const int bid = blockIdx.x;
    const int plane = bid >> 6;
    const int c = plane & 255;
    const int tile = bid & 63;
    const int th = (tile >> 3) * 32, tw = (tile & 7) * 32;
    const u16* A = outsum + (size_t)plane * HWPIX;
    const int tid = threadIdx.x;
    if (tid < 64) wk[tid] = wdw[c * 64 + tid];
    #pragma unroll
    for (int e = 0; e < 6; ++e) {
        const int idx = e * 256 + tid;
        if (idx < 39 * 39) {
            const int i = idx / 39, j = idx % 39;
            int eh, ew;
            const bool vh = extidx(th + i - 3, eh);
            const bool vw = extidx(tw + j - 3, ew);
            S[i][j] = (vh && vw) ? bf2f(A[eh * 256 + ew]) : 0.f;
        }
    }
    __syncthreads();
    const int ox = tid & 31, oy4 = (tid >> 5) * 4;
    u16* O = dwo + (size_t)plane * HWPIX;
    #pragma unroll
    for (int q = 0; q < 4; ++q) {
        const int oy = oy4 + q;
        float acc = 0.f;
        #pragma unroll
        for (int kh = 0; kh < 8; ++kh)
            #pragma unroll
            for (int kw = 0; kw < 8; ++kw)
                acc += wk[kh * 8 + kw] * S[oy + kh][ox + kw];
        O[(th + oy) * 256 + tw + ox] = f2bf(acc);
    }
}

// ---------------------------------------------------------------------------
extern "C" void kernel_launch(void* const* d_in, const int* in_sizes, int n_in,
                              void* d_out, int out_size, void* d_ws, size_t ws_size,
                              hipStream_t stream)
{
    const float* x     = (const float*)d_in[0];
    const float* w_qkv = (const float*)d_in[1];
    const float* w_l1  = (const float*)d_in[2];
    const float* bn1g  = (const float*)d_in[3];
    const float* bn1b  = (const float*)d_in[4];
    const float* w_l2  = (const float*)d_in[5];
    const float* bn2g  = (const float*)d_in[6];
    const float* bn2b  = (const float*)d_in[7];
    const float* w_dw  = (const float*)d_in[8];
    const float* bn3g  = (const float*)d_in[9];
    const float* bn3b  = (const float*)d_in[10];
    const float* w_pw  = (const float*)d_in[11];
    const float* rpb   = (const float*)d_in[12];
    float* out = (float*)d_out;
    char* ws = (char*)d_ws;

    // Diagnostic guard: refuse to run (clean absmax failure, no fault) if ws
    // is smaller than our 237 MB footprint.
    if (ws_size < (size_t)236587520) return;

    // region A [0, 64MiB): x_t, later dwt
    u16* x_t = (u16*)(ws + 0);
    u16* dwt = (u16*)(ws + 0);
    // region B [64MiB, 160MiB): qkv half (2x384x65536 bf16), later outsum bf16
    u16* qkvh   = (u16*)(ws + 67108864);
    u16* outsum = (u16*)(ws + 67108864);
    // region C [160MiB, 224MiB): local bf16, later dw_nchw bf16
    u16* localb  = (u16*)(ws + 167772160);
    u16* dw_nchw = (u16*)(ws + 167772160);
    // weights
    u16*   wl      = (u16*)(ws + 234881024);   // 1,179,648 B
    u16*   wq      = (u16*)(ws + 236060672);   //   393,216 B
    u16*   wpw     = (u16*)(ws + 236453888);   //   131,072 B
    float* bias_l  = (float*)(ws + 236584960); //     1,024 B
    float* bias_pw = (float*)(ws + 236585984); //     1,024 B
    u16*   zeros   = (u16*)(ws + 236587008);   //       512 B
    float* attnf = out;                        // d_out as f32 attn scratch

    prep_weights<<<1024, 256, 0, stream>>>(w_qkv, w_l1, bn1g, bn1b, w_l2, bn2g, bn2b,
                                           w_pw, bn3g, bn3b, wl, wq, wpw, bias_l, bias_pw, zeros);
    to_chlast<float><<<NPIX / 64, 256, 0, stream>>>(x, x_t);
    // local = fused conv3x3 + bias (bf16 out)
    gemm_conv<9, true, true><<<dim3(NPIX / 128, 2), 256, 0, stream>>>(
        x_t, wl, bias_l, localb, zeros, 0, 256);
    // qkv half A: oc 0..383 -> attn windows i1 in [0,16)
    gemm_conv<1, true, false><<<dim3(NPIX / 128, 3), 256, 0, stream>>>(
        x_t, wq, nullptr, qkvh, zeros, 0, 384);
    attn_win<<<16384, 64, 0, stream>>>(qkvh, rpb, attnf, 0);
    // qkv half B: oc 384..767 -> attn windows i1 in [16,32)
    gemm_conv<1, true, false><<<dim3(NPIX / 128, 3), 256, 0, stream>>>(
        x_t, wq, nullptr, qkvh, zeros, 384, 384);
    attn_win<<<16384, 64, 0, stream>>>(qkvh, rpb, attnf, 16);
    // pools + local add (reads d_out scratch, writes bf16 outsum over qkv)
    pool_add<<<32768, 256, 0, stream>>>(attnf, localb, outsum);
    // depthwise 8x8 (writes over local region)
    dwconv<<<32768, 256, 0, stream>>>(outsum, w_dw, dw_nchw);
    // channels-last transform of dw output (writes over x_t region)
    to_chlast<u16><<<NPIX / 64, 256, 0, stream>>>(dw_nchw, dwt);
    // pointwise GEMM + bias -> final f32 output (rewrites all of d_out)
    gemm_conv<1, false, true><<<dim3(NPIX / 128, 2), 256, 0, stream>>>(
        dwt, wpw, bias_pw, out, zeros, 0, 256);
}